// Round 1
// baseline (907.507 us; speedup 1.0000x reference)
//
#include <hip/hip_runtime.h>
#include <stdint.h>

// LocalWindowAttention: B=2,T=4096,D=2048,H=16,HK=4,HD=128,WIN=512
// Pipeline: bf16 convert/transpose -> QKV GEMMs -> chunked (S=QK^T, masked
// softmax, O=PV) -> Wo GEMM. All GEMMs share one 128x128x32 bf16 MFMA core.

typedef unsigned short u16;
typedef __attribute__((ext_vector_type(8))) short frag8;   // 8 bf16 = 4 VGPRs
typedef __attribute__((ext_vector_type(4))) float f32x4;   // MFMA acc

#define TILE 128
#define LDSS 40   // LDS row stride in shorts (32 + 8 pad -> conflict-free b128 reads)

__device__ __forceinline__ u16 f2bf(float f) {
  union { float f; unsigned u; } c; c.f = f;
  unsigned u = c.u;
  return (u16)((u + 0x7fffu + ((u >> 16) & 1u)) >> 16);
}

// ---- shared 128x128 GEMM core: A [M,K] row-major bf16, Bt = B^T [N,K] row-major bf16
__device__ __forceinline__ void gemm_core(const u16* __restrict__ A, int lda,
                                          const u16* __restrict__ Bt, int ldb,
                                          int K, u16* As, u16* Bs, f32x4 acc[4][4]) {
  const int tid = threadIdx.x;
  const int lane = tid & 63, wave = tid >> 6;
  const int wr = wave >> 1, wc = wave & 1;
  const int quad = lane >> 4, l16 = lane & 15;
#pragma unroll
  for (int i = 0; i < 4; ++i)
#pragma unroll
    for (int j = 0; j < 4; ++j) acc[i][j] = (f32x4){0.f, 0.f, 0.f, 0.f};

  for (int k0 = 0; k0 < K; k0 += 32) {
    // stage A and B^T tiles: 128 rows x 32 k each, 16B per thread-chunk
#pragma unroll
    for (int p = 0; p < 2; ++p) {
      int c = p * 256 + tid;
      int row = c >> 2, off = (c & 3) * 8;           // off in shorts
      int4 da = *(const int4*)(A + (long)row * lda + k0 + off);
      int4 db = *(const int4*)(Bt + (long)row * ldb + k0 + off);
      *(int4*)(As + row * LDSS + off) = da;
      *(int4*)(Bs + row * LDSS + off) = db;
    }
    __syncthreads();
    frag8 af[4], bf[4];
#pragma unroll
    for (int i = 0; i < 4; ++i)
      af[i] = *(const frag8*)(As + (wr * 64 + i * 16 + l16) * LDSS + quad * 8);
#pragma unroll
    for (int j = 0; j < 4; ++j)
      bf[j] = *(const frag8*)(Bs + (wc * 64 + j * 16 + l16) * LDSS + quad * 8);
#pragma unroll
    for (int i = 0; i < 4; ++i)
#pragma unroll
      for (int j = 0; j < 4; ++j)
        acc[i][j] = __builtin_amdgcn_mfma_f32_16x16x32_bf16(af[i], bf[j], acc[i][j], 0, 0, 0);
    __syncthreads();
  }
}

// ---- epilogue helpers (C/D: col = lane&15, row = quad*4 + reg)
#define EPI_COORDS                                             \
  const int lane = threadIdx.x & 63, wave = threadIdx.x >> 6;  \
  const int wr = wave >> 1, wc = wave & 1;                     \
  const int quad = lane >> 4, l16 = lane & 15;

__global__ __launch_bounds__(256) void k_gemm_bf16(const u16* __restrict__ A, int lda,
                                                   const u16* __restrict__ Bt, int ldb,
                                                   u16* __restrict__ C, int ldc, int K) {
  __shared__ alignas(16) u16 smem[2 * TILE * LDSS];
  f32x4 acc[4][4];
  gemm_core(A + (long)blockIdx.x * TILE * lda, lda,
            Bt + (long)blockIdx.y * TILE * ldb, ldb, K, smem, smem + TILE * LDSS, acc);
  EPI_COORDS
  u16* Ct = C + (long)blockIdx.x * TILE * ldc + (long)blockIdx.y * TILE;
#pragma unroll
  for (int i = 0; i < 4; ++i)
#pragma unroll
    for (int j = 0; j < 4; ++j) {
      int r0 = wr * 64 + i * 16 + quad * 4, cc = wc * 64 + j * 16 + l16;
#pragma unroll
      for (int r = 0; r < 4; ++r) Ct[(long)(r0 + r) * ldc + cc] = f2bf(acc[i][j][r]);
    }
}

// writes C^T [N,K-major]: contiguous 4-element store per acc tile
__global__ __launch_bounds__(256) void k_gemm_bf16t(const u16* __restrict__ A, int lda,
                                                    const u16* __restrict__ Bt, int ldb,
                                                    u16* __restrict__ Ct, int ldct, int K) {
  __shared__ alignas(16) u16 smem[2 * TILE * LDSS];
  f32x4 acc[4][4];
  gemm_core(A + (long)blockIdx.x * TILE * lda, lda,
            Bt + (long)blockIdx.y * TILE * ldb, ldb, K, smem, smem + TILE * LDSS, acc);
  EPI_COORDS
  u16* Cb = Ct + (long)blockIdx.y * TILE * ldct + (long)blockIdx.x * TILE;
#pragma unroll
  for (int i = 0; i < 4; ++i)
#pragma unroll
    for (int j = 0; j < 4; ++j) {
      int n = wc * 64 + j * 16 + l16, m0 = wr * 64 + i * 16 + quad * 4;
      ushort4 o;
      o.x = f2bf(acc[i][j][0]); o.y = f2bf(acc[i][j][1]);
      o.z = f2bf(acc[i][j][2]); o.w = f2bf(acc[i][j][3]);
      *(ushort4*)(Cb + (long)n * ldct + m0) = o;
    }
}

__global__ __launch_bounds__(256) void k_gemm_f32(const u16* __restrict__ A, int lda,
                                                  const u16* __restrict__ Bt, int ldb,
                                                  float* __restrict__ C, int ldc, int K) {
  __shared__ alignas(16) u16 smem[2 * TILE * LDSS];
  f32x4 acc[4][4];
  gemm_core(A + (long)blockIdx.x * TILE * lda, lda,
            Bt + (long)blockIdx.y * TILE * ldb, ldb, K, smem, smem + TILE * LDSS, acc);
  EPI_COORDS
  float* Ct = C + (long)blockIdx.x * TILE * ldc + (long)blockIdx.y * TILE;
#pragma unroll
  for (int i = 0; i < 4; ++i)
#pragma unroll
    for (int j = 0; j < 4; ++j) {
      int r0 = wr * 64 + i * 16 + quad * 4, cc = wc * 64 + j * 16 + l16;
#pragma unroll
      for (int r = 0; r < 4; ++r) Ct[(long)(r0 + r) * ldc + cc] = acc[i][j][r];
    }
}

// S = q @ kcat^T per (b, blk, h) batch. grid (4, 8, chunk)
__global__ __launch_bounds__(256) void k_gemm_S(const u16* __restrict__ Q,
                                                const u16* __restrict__ Kb,
                                                float* __restrict__ S, int z0) {
  __shared__ alignas(16) u16 smem[2 * TILE * LDSS];
  int z = z0 + blockIdx.z;
  int b = z >> 7, blk = (z >> 4) & 7, h = z & 15, hk = h >> 2;
  const u16* At = Q + (long)(b * 4096 + blk * 512) * 2048 + h * 128 + (long)blockIdx.x * TILE * 2048;
  const u16* Bt = Kb + ((long)(b * 4096 + blk * 512) - 512) * 512 + hk * 128 + (long)blockIdx.y * TILE * 512;
  f32x4 acc[4][4];
  gemm_core(At, 2048, Bt, 512, 128, smem, smem + TILE * LDSS, acc);
  EPI_COORDS
  float* Ct = S + (long)blockIdx.z * (512 * 1024) + (long)blockIdx.x * TILE * 1024 + (long)blockIdx.y * TILE;
#pragma unroll
  for (int i = 0; i < 4; ++i)
#pragma unroll
    for (int j = 0; j < 4; ++j) {
      int r0 = wr * 64 + i * 16 + quad * 4, cc = wc * 64 + j * 16 + l16;
#pragma unroll
      for (int r = 0; r < 4; ++r) Ct[(long)(r0 + r) * 1024 + cc] = acc[i][j][r];
    }
}

// masked softmax over 1024-wide rows; one block per (local batch, row)
__global__ __launch_bounds__(256) void k_softmax(const float* __restrict__ S,
                                                 u16* __restrict__ P, int z0) {
  __shared__ float sm[8];
  int bid = blockIdx.x;
  int r = bid & 511;
  int z = z0 + (bid >> 9);
  int blk = (z >> 4) & 7;
  int tid = threadIdx.x;
  const float scale = 0.08838834764831845f;  // 1/sqrt(128)
  float4 sv = ((const float4*)(S + (long)bid * 1024))[tid];
  float v[4];
#pragma unroll
  for (int e = 0; e < 4; ++e) {
    int cc = tid * 4 + e;
    bool ok = (cc < 512) ? (cc > r && blk > 0) : ((cc - 512) <= r);
    v[e] = ok ? (&sv.x)[e] * scale : -INFINITY;
  }
  float m = fmaxf(fmaxf(v[0], v[1]), fmaxf(v[2], v[3]));
  for (int o = 32; o; o >>= 1) m = fmaxf(m, __shfl_xor(m, o));
  int wave = tid >> 6;
  if ((tid & 63) == 0) sm[wave] = m;
  __syncthreads();
  m = fmaxf(fmaxf(sm[0], sm[1]), fmaxf(sm[2], sm[3]));
  __syncthreads();
  float e4[4], s = 0.f;
#pragma unroll
  for (int e = 0; e < 4; ++e) { e4[e] = __expf(v[e] - m); s += e4[e]; }
  for (int o = 32; o; o >>= 1) s += __shfl_xor(s, o);
  if ((tid & 63) == 0) sm[4 + wave] = s;
  __syncthreads();
  s = (sm[4] + sm[5]) + (sm[6] + sm[7]);
  float inv = 1.0f / s;
  ushort4 o4;
  o4.x = f2bf(e4[0] * inv); o4.y = f2bf(e4[1] * inv);
  o4.z = f2bf(e4[2] * inv); o4.w = f2bf(e4[3] * inv);
  ((ushort4*)(P + (long)bid * 1024))[tid] = o4;
}

// O = P @ vcat per (b, blk, h). grid (4, 1, chunk)
__global__ __launch_bounds__(256) void k_gemm_PV(const u16* __restrict__ P,
                                                 const u16* __restrict__ vT,
                                                 u16* __restrict__ O, int z0) {
  __shared__ alignas(16) u16 smem[2 * TILE * LDSS];
  int z = z0 + blockIdx.z;
  int b = z >> 7, blk = (z >> 4) & 7, h = z & 15, hk = h >> 2;
  const u16* At = P + (long)blockIdx.z * (512 * 1024) + (long)blockIdx.x * TILE * 1024;
  const u16* Bt = vT + (long)(hk * 128) * 8192 + ((long)(b * 4096 + blk * 512) - 512);
  f32x4 acc[4][4];
  gemm_core(At, 1024, Bt, 8192, 1024, smem, smem + TILE * LDSS, acc);
  EPI_COORDS
  u16* Ct = O + (long)(b * 4096 + blk * 512) * 2048 + h * 128 + (long)blockIdx.x * TILE * 2048;
#pragma unroll
  for (int i = 0; i < 4; ++i)
#pragma unroll
    for (int j = 0; j < 4; ++j) {
      int r0 = wr * 64 + i * 16 + quad * 4, cc = wc * 64 + j * 16 + l16;
#pragma unroll
      for (int r = 0; r < 4; ++r) Ct[(long)(r0 + r) * 2048 + cc] = f2bf(acc[i][j][r]);
    }
}

__global__ void k_convert(const float4* __restrict__ x, ushort4* __restrict__ xb) {
  int i = blockIdx.x * 256 + threadIdx.x;
  float4 f = x[i];
  ushort4 o;
  o.x = f2bf(f.x); o.y = f2bf(f.y); o.z = f2bf(f.z); o.w = f2bf(f.w);
  xb[i] = o;
}

// W [K,N] fp32 -> W^T [N,K] bf16
__global__ void k_transpose(const float* __restrict__ W, u16* __restrict__ WT, int K, int N) {
  __shared__ float sh[32][33];
  int n0 = blockIdx.x * 32, k0 = blockIdx.y * 32;
  int tx = threadIdx.x, ty = threadIdx.y;  // (32, 8)
#pragma unroll
  for (int i = 0; i < 32; i += 8) sh[ty + i][tx] = W[(long)(k0 + ty + i) * N + n0 + tx];
  __syncthreads();
#pragma unroll
  for (int i = 0; i < 32; i += 8) WT[(long)(n0 + ty + i) * K + k0 + tx] = f2bf(sh[tx][ty + i]);
}

extern "C" void kernel_launch(void* const* d_in, const int* in_sizes, int n_in,
                              void* d_out, int out_size, void* d_ws, size_t ws_size,
                              hipStream_t stream) {
  const float* x  = (const float*)d_in[0];
  const float* Wq = (const float*)d_in[1];
  const float* Wk = (const float*)d_in[2];
  const float* Wv = (const float*)d_in[3];
  const float* Wo = (const float*)d_in[4];
  float* out = (float*)d_out;

  const long BT = 8192, D = 2048, NKV = 512;
  size_t off = 0;
  auto alloc = [&](size_t bytes) -> char* {
    off = (off + 255) & ~(size_t)255;
    char* p = (char*)d_ws + off;
    off += bytes;
    return p;
  };

  // fixed buffers: xb(=Oattn) + 4 W^T + q + k + vT  ~= 104.9 MB
  size_t fixedB = (size_t)BT * D * 2 + D * D * 2 + NKV * D * 2 + NKV * D * 2 + D * D * 2 +
                  (size_t)BT * D * 2 + BT * NKV * 2 + NKV * BT * 2 + 12 * 256;
  int chunk = 256;  // batches of (b,blk,h); S fp32 + P bf16 = 3 MiB/batch
  while (chunk > 1 && fixedB + (size_t)chunk * (512 * 1024 * 6) > ws_size) chunk >>= 1;

  float* S  = (float*)alloc((size_t)chunk * 512 * 1024 * 4);
  u16* P    = (u16*)alloc((size_t)chunk * 512 * 1024 * 2);
  u16* xb   = (u16*)alloc((size_t)BT * D * 2);  // reused as attention output
  u16* WqT  = (u16*)alloc((size_t)D * D * 2);
  u16* WkT  = (u16*)alloc((size_t)NKV * D * 2);
  u16* WvT  = (u16*)alloc((size_t)NKV * D * 2);
  u16* WoT  = (u16*)alloc((size_t)D * D * 2);
  u16* qb   = (u16*)alloc((size_t)BT * D * 2);
  u16* kb   = (u16*)alloc((size_t)BT * NKV * 2);  // preceded by qb: negative-window reads stay finite
  u16* vT   = (u16*)alloc((size_t)NKV * BT * 2);  // preceded by kb: same
  u16* Oa   = xb;

  k_convert<<<16384, 256, 0, stream>>>((const float4*)x, (ushort4*)xb);
  dim3 tb(32, 8);
  k_transpose<<<dim3(64, 64), tb, 0, stream>>>(Wq, WqT, 2048, 2048);
  k_transpose<<<dim3(16, 64), tb, 0, stream>>>(Wk, WkT, 2048, 512);
  k_transpose<<<dim3(16, 64), tb, 0, stream>>>(Wv, WvT, 2048, 512);
  k_transpose<<<dim3(64, 64), tb, 0, stream>>>(Wo, WoT, 2048, 2048);

  k_gemm_bf16 <<<dim3(64, 16), 256, 0, stream>>>(xb, 2048, WqT, 2048, qb, 2048, 2048);
  k_gemm_bf16 <<<dim3(64, 4),  256, 0, stream>>>(xb, 2048, WkT, 2048, kb, 512, 2048);
  k_gemm_bf16t<<<dim3(64, 4),  256, 0, stream>>>(xb, 2048, WvT, 2048, vT, 8192, 2048);

  for (int z0 = 0; z0 < 256; z0 += chunk) {
    k_gemm_S <<<dim3(4, 8, chunk), 256, 0, stream>>>(qb, kb, S, z0);
    k_softmax<<<chunk * 512, 256, 0, stream>>>(S, P, z0);
    k_gemm_PV<<<dim3(4, 1, chunk), 256, 0, stream>>>(P, vT, Oa, z0);
  }

  k_gemm_f32<<<dim3(64, 16), 256, 0, stream>>>(Oa, 2048, WoT, 2048, out, 2048, 2048);
}

// Round 2
// 608.255 us; speedup vs baseline: 1.4920x; 1.4920x over previous
//
#include <hip/hip_runtime.h>
#include <stdint.h>

// LocalWindowAttention: B=2,T=4096,D=2048,H=16,HK=4,HD=128,WIN=512
// R2: m97-style global_load_lds GEMM core + fused flash-style attention
// (online softmax, K/V chunks staged in LDS, P overlays K buffer).

typedef unsigned short u16;
typedef __attribute__((ext_vector_type(8))) short frag8;   // 8 bf16 = 4 VGPRs
typedef __attribute__((ext_vector_type(4))) float f32x4;   // MFMA acc

#define TILE 128

__device__ __forceinline__ u16 f2bf(float f) {
  union { float f; unsigned u; } c; c.f = f;
  unsigned u = c.u;
  return (u16)((u + 0x7fffu + ((u >> 16) & 1u)) >> 16);
}

// async global->LDS, 16B per lane; LDS dest = wave-uniform base + lane*16
__device__ __forceinline__ void async16(const u16* g, u16* l) {
  __builtin_amdgcn_global_load_lds((const __attribute__((address_space(1))) void*)g,
                                   (__attribute__((address_space(3))) void*)l, 16, 0, 0);
}

// ---- m97-style 128x128 GEMM core: A [M,K] row-major bf16, Bt = B^T [N,K] row-major
__device__ __forceinline__ void gemm_core(const u16* __restrict__ A, int lda,
                                          const u16* __restrict__ Bt, int ldb,
                                          int K, u16* As, u16* Bs, f32x4 acc[4][4]) {
  const int tid = threadIdx.x;
  const int lane = tid & 63, wave = tid >> 6;
  const int wr = wave >> 1, wc = wave & 1;
  const int quad = lane >> 4, l16 = lane & 15;
#pragma unroll
  for (int i = 0; i < 4; ++i)
#pragma unroll
    for (int j = 0; j < 4; ++j) acc[i][j] = (f32x4){0.f, 0.f, 0.f, 0.f};

  const int row0 = tid >> 2, offc = (tid & 3) * 8;  // 128 rows x 32 k, 16B chunks
  for (int k0 = 0; k0 < K; k0 += 32) {
#pragma unroll
    for (int r = 0; r < 2; ++r) {
      int row = r * 64 + row0;
      async16(A + (long)row * lda + k0 + offc, As + r * 2048 + wave * 512);
      async16(Bt + (long)row * ldb + k0 + offc, Bs + r * 2048 + wave * 512);
    }
    __syncthreads();
    frag8 af[4], bf[4];
#pragma unroll
    for (int i = 0; i < 4; ++i)
      af[i] = *(const frag8*)(As + (wr * 64 + i * 16 + l16) * 32 + quad * 8);
#pragma unroll
    for (int j = 0; j < 4; ++j)
      bf[j] = *(const frag8*)(Bs + (wc * 64 + j * 16 + l16) * 32 + quad * 8);
#pragma unroll
    for (int i = 0; i < 4; ++i)
#pragma unroll
      for (int j = 0; j < 4; ++j)
        acc[i][j] = __builtin_amdgcn_mfma_f32_16x16x32_bf16(af[i], bf[j], acc[i][j], 0, 0, 0);
    __syncthreads();
  }
}

#define EPI_COORDS                                             \
  const int lane = threadIdx.x & 63, wave = threadIdx.x >> 6;  \
  const int wr = wave >> 1, wc = wave & 1;                     \
  const int quad = lane >> 4, l16 = lane & 15;

__global__ __launch_bounds__(256) void k_gemm_bf16(const u16* __restrict__ A, int lda,
                                                   const u16* __restrict__ Bt, int ldb,
                                                   u16* __restrict__ C, int ldc, int K) {
  __shared__ alignas(16) u16 smem[2 * TILE * 32];
  f32x4 acc[4][4];
  gemm_core(A + (long)blockIdx.x * TILE * lda, lda,
            Bt + (long)blockIdx.y * TILE * ldb, ldb, K, smem, smem + TILE * 32, acc);
  EPI_COORDS
  u16* Ct = C + (long)blockIdx.x * TILE * ldc + (long)blockIdx.y * TILE;
#pragma unroll
  for (int i = 0; i < 4; ++i)
#pragma unroll
    for (int j = 0; j < 4; ++j) {
      int r0 = wr * 64 + i * 16 + quad * 4, cc = wc * 64 + j * 16 + l16;
#pragma unroll
      for (int r = 0; r < 4; ++r) Ct[(long)(r0 + r) * ldc + cc] = f2bf(acc[i][j][r]);
    }
}

// writes C^T: contiguous 4-element store per acc tile (for V^T layout)
__global__ __launch_bounds__(256) void k_gemm_bf16t(const u16* __restrict__ A, int lda,
                                                    const u16* __restrict__ Bt, int ldb,
                                                    u16* __restrict__ Ct, int ldct, int K) {
  __shared__ alignas(16) u16 smem[2 * TILE * 32];
  f32x4 acc[4][4];
  gemm_core(A + (long)blockIdx.x * TILE * lda, lda,
            Bt + (long)blockIdx.y * TILE * ldb, ldb, K, smem, smem + TILE * 32, acc);
  EPI_COORDS
  u16* Cb = Ct + (long)blockIdx.y * TILE * ldct + (long)blockIdx.x * TILE;
#pragma unroll
  for (int i = 0; i < 4; ++i)
#pragma unroll
    for (int j = 0; j < 4; ++j) {
      int n = wc * 64 + j * 16 + l16, m0 = wr * 64 + i * 16 + quad * 4;
      ushort4 o;
      o.x = f2bf(acc[i][j][0]); o.y = f2bf(acc[i][j][1]);
      o.z = f2bf(acc[i][j][2]); o.w = f2bf(acc[i][j][3]);
      *(ushort4*)(Cb + (long)n * ldct + m0) = o;
    }
}

__global__ __launch_bounds__(256) void k_gemm_f32(const u16* __restrict__ A, int lda,
                                                  const u16* __restrict__ Bt, int ldb,
                                                  float* __restrict__ C, int ldc, int K) {
  __shared__ alignas(16) u16 smem[2 * TILE * 32];
  f32x4 acc[4][4];
  gemm_core(A + (long)blockIdx.x * TILE * lda, lda,
            Bt + (long)blockIdx.y * TILE * ldb, ldb, K, smem, smem + TILE * 32, acc);
  EPI_COORDS
  float* Ct = C + (long)blockIdx.x * TILE * ldc + (long)blockIdx.y * TILE;
#pragma unroll
  for (int i = 0; i < 4; ++i)
#pragma unroll
    for (int j = 0; j < 4; ++j) {
      int r0 = wr * 64 + i * 16 + quad * 4, cc = wc * 64 + j * 16 + l16;
#pragma unroll
      for (int r = 0; r < 4; ++r) Ct[(long)(r0 + r) * ldc + cc] = acc[i][j][r];
    }
}

// ---- fused local-window attention --------------------------------------
// grid: x = qi (q 128-row block, 0..3), y = blk (0..7), z = b*16 + h (0..31)
// Each wave owns 32 query rows (2 row-tiles x 8 col-tiles). Online softmax
// state (m, l) per row lives in registers, replicated across each 16-lane group.
// Key window processed in 128-key chunks; chunk ci covers concat-window cols
// [ci*128, ci*128+128): ci<4 = prev block (skip if blk==0), ci>=4 = own block.
// Active chunks: ci in [qi, 4+qi]; ci==qi / ci==4+qi are the two diagonals.
__global__ __launch_bounds__(256, 2) void k_attn(const u16* __restrict__ qb,
                                                 const u16* __restrict__ kb,
                                                 const u16* __restrict__ vT,
                                                 u16* __restrict__ O) {
  __shared__ alignas(16) u16 Ks[128 * 128];  // [key][hd]; P overlays after S-phase
  __shared__ alignas(16) u16 Vs[128 * 128];  // [hd][key]
  const int tid = threadIdx.x, lane = tid & 63, wave = tid >> 6;
  const int quad = lane >> 4, l16 = lane & 15;
  const int qi = blockIdx.x, blk = blockIdx.y;
  const int b = blockIdx.z >> 4, h = blockIdx.z & 15, hk = h >> 2;
  const long tok_q = (long)b * 4096 + blk * 512 + qi * 128;
  const float scale = 0.08838834764831845f;  // 1/sqrt(128)

  // Q fragments for this wave's 32 rows, all of HD=128 (held across chunks)
  frag8 qf[2][4];
#pragma unroll
  for (int i = 0; i < 2; ++i)
#pragma unroll
    for (int kt = 0; kt < 4; ++kt)
      qf[i][kt] = *(const frag8*)(qb + (tok_q + wave * 32 + i * 16 + l16) * 2048 +
                                  h * 128 + kt * 32 + quad * 8);

  f32x4 o_acc[2][8];
  float m_r[2][4], l_r[2][4];
#pragma unroll
  for (int i = 0; i < 2; ++i) {
#pragma unroll
    for (int j = 0; j < 8; ++j) o_acc[i][j] = (f32x4){0.f, 0.f, 0.f, 0.f};
#pragma unroll
    for (int r = 0; r < 4; ++r) { m_r[i][r] = -1e30f; l_r[i][r] = 0.f; }
  }

  const int row_s = tid >> 4, off_s = (tid & 15) * 8;  // staging coords (128x128)
  u16* PsW = Ks + wave * 4096;                         // this wave's 32x128 P region

  for (int ci = (blk ? qi : 4); ci <= 4 + qi; ++ci) {
    const long tok_k = (long)b * 4096 + (blk - 1) * 512 + ci * 128;
    const int mode = (ci == qi) ? 1 : ((ci == 4 + qi) ? 2 : 0);  // 1: lk>rl, 2: lk<=rl

    // stage K chunk [128 key][128 hd] and V chunk [128 hd][128 key]
#pragma unroll
    for (int r2 = 0; r2 < 8; ++r2) {
      int row = r2 * 16 + row_s;
      async16(kb + (tok_k + row) * 512 + hk * 128 + off_s, Ks + r2 * 2048 + wave * 512);
      async16(vT + ((long)hk * 128 + row) * 8192 + tok_k + off_s, Vs + r2 * 2048 + wave * 512);
    }
    __syncthreads();

    // S = Q @ K^T  (32 rows x 128 keys per wave)
    f32x4 s_acc[2][8];
#pragma unroll
    for (int i = 0; i < 2; ++i)
#pragma unroll
      for (int j = 0; j < 8; ++j) s_acc[i][j] = (f32x4){0.f, 0.f, 0.f, 0.f};
#pragma unroll
    for (int kt = 0; kt < 4; ++kt) {
      frag8 bfr[8];
#pragma unroll
      for (int j = 0; j < 8; ++j)
        bfr[j] = *(const frag8*)(Ks + (j * 16 + l16) * 128 + kt * 32 + quad * 8);
#pragma unroll
      for (int i = 0; i < 2; ++i)
#pragma unroll
        for (int j = 0; j < 8; ++j)
          s_acc[i][j] = __builtin_amdgcn_mfma_f32_16x16x32_bf16(qf[i][kt], bfr[j], s_acc[i][j], 0, 0, 0);
    }

    // scale + mask + per-row chunk max
    float mc[2][4];
#pragma unroll
    for (int i = 0; i < 2; ++i)
#pragma unroll
      for (int r = 0; r < 4; ++r) mc[i][r] = -1e30f;
#pragma unroll
    for (int i = 0; i < 2; ++i)
#pragma unroll
      for (int j = 0; j < 8; ++j)
#pragma unroll
        for (int r = 0; r < 4; ++r) {
          int rl = wave * 32 + i * 16 + quad * 4 + r;  // row within 128-q-block
          int lk = j * 16 + l16;                       // key within chunk
          bool ok = (mode == 0) || (mode == 1 ? (lk > rl) : (lk <= rl));
          float s = ok ? s_acc[i][j][r] * scale : -1e30f;
          s_acc[i][j][r] = s;
          mc[i][r] = fmaxf(mc[i][r], s);
        }
#pragma unroll
    for (int o = 1; o < 16; o <<= 1)
#pragma unroll
      for (int i = 0; i < 2; ++i)
#pragma unroll
        for (int r = 0; r < 4; ++r)
          mc[i][r] = fmaxf(mc[i][r], __shfl_xor(mc[i][r], o));

    // online-softmax update
    float alpha[2][4];
#pragma unroll
    for (int i = 0; i < 2; ++i)
#pragma unroll
      for (int r = 0; r < 4; ++r) {
        float mn = fmaxf(m_r[i][r], mc[i][r]);
        alpha[i][r] = __expf(m_r[i][r] - mn);  // m=-1e30 & mn=-1e30 -> exp(0)=1, l=0 anyway
        m_r[i][r] = mn;
        l_r[i][r] *= alpha[i][r];
      }
#pragma unroll
    for (int i = 0; i < 2; ++i)
#pragma unroll
      for (int j = 0; j < 8; ++j)
#pragma unroll
        for (int r = 0; r < 4; ++r) o_acc[i][j][r] *= alpha[i][r];

    float ps[2][4];
#pragma unroll
    for (int i = 0; i < 2; ++i)
#pragma unroll
      for (int r = 0; r < 4; ++r) ps[i][r] = 0.f;
#pragma unroll
    for (int i = 0; i < 2; ++i)
#pragma unroll
      for (int j = 0; j < 8; ++j)
#pragma unroll
        for (int r = 0; r < 4; ++r) {
          float s = s_acc[i][j][r];
          float e = __expf(s - m_r[i][r]);
          e = (s == -1e30f) ? 0.f : e;  // explicit mask gate (handles all-masked rows)
          s_acc[i][j][r] = e;
          ps[i][r] += e;
        }
#pragma unroll
    for (int o = 1; o < 16; o <<= 1)
#pragma unroll
      for (int i = 0; i < 2; ++i)
#pragma unroll
        for (int r = 0; r < 4; ++r) ps[i][r] += __shfl_xor(ps[i][r], o);
#pragma unroll
    for (int i = 0; i < 2; ++i)
#pragma unroll
      for (int r = 0; r < 4; ++r) l_r[i][r] += ps[i][r];

    __syncthreads();  // all waves done reading Ks before P overlays it

    // P: C-layout regs -> LDS [row][key] (wave-private region)
#pragma unroll
    for (int i = 0; i < 2; ++i)
#pragma unroll
      for (int j = 0; j < 8; ++j)
#pragma unroll
        for (int r = 0; r < 4; ++r)
          PsW[(i * 16 + quad * 4 + r) * 128 + j * 16 + l16] = f2bf(s_acc[i][j][r]);

    // O += P @ V
#pragma unroll
    for (int kt = 0; kt < 4; ++kt) {
      frag8 pf[2], vf[8];
#pragma unroll
      for (int i = 0; i < 2; ++i)
        pf[i] = *(const frag8*)(PsW + (i * 16 + l16) * 128 + kt * 32 + quad * 8);
#pragma unroll
      for (int j = 0; j < 8; ++j)
        vf[j] = *(const frag8*)(Vs + (j * 16 + l16) * 128 + kt * 32 + quad * 8);
#pragma unroll
      for (int i = 0; i < 2; ++i)
#pragma unroll
        for (int j = 0; j < 8; ++j)
          o_acc[i][j] = __builtin_amdgcn_mfma_f32_16x16x32_bf16(pf[i], vf[j], o_acc[i][j], 0, 0, 0);
    }
    __syncthreads();  // before next chunk's staging overwrites Ks/Vs
  }

  // epilogue: O / l
  float inv[2][4];
#pragma unroll
  for (int i = 0; i < 2; ++i)
#pragma unroll
    for (int r = 0; r < 4; ++r) inv[i][r] = 1.0f / l_r[i][r];
#pragma unroll
  for (int i = 0; i < 2; ++i)
#pragma unroll
    for (int j = 0; j < 8; ++j)
#pragma unroll
      for (int r = 0; r < 4; ++r) {
        long row = tok_q + wave * 32 + i * 16 + quad * 4 + r;
        O[row * 2048 + h * 128 + j * 16 + l16] = f2bf(o_acc[i][j][r] * inv[i][r]);
      }
}

__global__ void k_convert(const float4* __restrict__ x, ushort4* __restrict__ xb) {
  int i = blockIdx.x * 256 + threadIdx.x;
  float4 f = x[i];
  ushort4 o;
  o.x = f2bf(f.x); o.y = f2bf(f.y); o.z = f2bf(f.z); o.w = f2bf(f.w);
  xb[i] = o;
}

// W [K,N] fp32 -> W^T [N,K] bf16
__global__ void k_transpose(const float* __restrict__ W, u16* __restrict__ WT, int K, int N) {
  __shared__ float sh[32][33];
  int n0 = blockIdx.x * 32, k0 = blockIdx.y * 32;
  int tx = threadIdx.x, ty = threadIdx.y;  // (32, 8)
#pragma unroll
  for (int i = 0; i < 32; i += 8) sh[ty + i][tx] = W[(long)(k0 + ty + i) * N + n0 + tx];
  __syncthreads();
#pragma unroll
  for (int i = 0; i < 32; i += 8) WT[(long)(n0 + ty + i) * K + k0 + tx] = f2bf(sh[tx][ty + i]);
}

extern "C" void kernel_launch(void* const* d_in, const int* in_sizes, int n_in,
                              void* d_out, int out_size, void* d_ws, size_t ws_size,
                              hipStream_t stream) {
  const float* x  = (const float*)d_in[0];
  const float* Wq = (const float*)d_in[1];
  const float* Wk = (const float*)d_in[2];
  const float* Wv = (const float*)d_in[3];
  const float* Wo = (const float*)d_in[4];
  float* out = (float*)d_out;

  const long BT = 8192, D = 2048, NKV = 512;
  size_t off = 0;
  auto alloc = [&](size_t bytes) -> char* {
    off = (off + 255) & ~(size_t)255;
    char* p = (char*)d_ws + off;
    off += bytes;
    return p;
  };

  u16* xb  = (u16*)alloc((size_t)BT * D * 2);  // reused as attention output
  u16* WqT = (u16*)alloc((size_t)D * D * 2);
  u16* WkT = (u16*)alloc((size_t)NKV * D * 2);
  u16* WvT = (u16*)alloc((size_t)NKV * D * 2);
  u16* WoT = (u16*)alloc((size_t)D * D * 2);
  u16* qb  = (u16*)alloc((size_t)BT * D * 2);
  u16* kb  = (u16*)alloc((size_t)BT * NKV * 2);
  u16* vT  = (u16*)alloc((size_t)NKV * BT * 2);
  u16* Oa  = xb;

  k_convert<<<16384, 256, 0, stream>>>((const float4*)x, (ushort4*)xb);
  dim3 tb(32, 8);
  k_transpose<<<dim3(64, 64), tb, 0, stream>>>(Wq, WqT, 2048, 2048);
  k_transpose<<<dim3(16, 64), tb, 0, stream>>>(Wk, WkT, 2048, 512);
  k_transpose<<<dim3(16, 64), tb, 0, stream>>>(Wv, WvT, 2048, 512);
  k_transpose<<<dim3(64, 64), tb, 0, stream>>>(Wo, WoT, 2048, 2048);

  k_gemm_bf16 <<<dim3(64, 16), 256, 0, stream>>>(xb, 2048, WqT, 2048, qb, 2048, 2048);
  k_gemm_bf16 <<<dim3(64, 4),  256, 0, stream>>>(xb, 2048, WkT, 2048, kb, 512, 2048);
  k_gemm_bf16t<<<dim3(64, 4),  256, 0, stream>>>(xb, 2048, WvT, 2048, vT, 8192, 2048);

  k_attn<<<dim3(4, 8, 32), 256, 0, stream>>>(qb, kb, vT, Oa);

  k_gemm_f32<<<dim3(64, 16), 256, 0, stream>>>(Oa, 2048, WoT, 2048, out, 2048, 2048);
}